// Round 4
// baseline (1942.119 us; speedup 1.0000x reference)
//
#include <hip/hip_runtime.h>

#define Bn 8
#define Mn 2048
#define Nn 2048
#define Cn 256
#define Np1 2049
#define Mp1 2049
#define SINK_ITERS 20
#define NORM   (-8.3177661667193428f)   /* -log(4096) */
#define LOGBIN (-0.6931471805599453f)   /* log(2048) - log(4096) */

typedef __bf16 v8bf __attribute__((ext_vector_type(8)));
typedef float  v4f  __attribute__((ext_vector_type(4)));

__device__ __forceinline__ float bf2f(unsigned short h){
  return __uint_as_float(((unsigned)h) << 16);
}
__device__ __forceinline__ unsigned short f2bf(float f){
  unsigned u = __float_as_uint(f);
  return (unsigned short)((u + 0x7FFFu + ((u >> 16) & 1u)) >> 16);
}
// S element load/store, generic over bf16 (ws path) and fp32 (in-d_out fallback path)
__device__ __forceinline__ float ldS(const float* p){ return *p; }
__device__ __forceinline__ float ldS(const unsigned short* p){ return bf2f(*p); }
__device__ __forceinline__ void  stS(float* p, float x){ *p = x; }
__device__ __forceinline__ void  stS(unsigned short* p, float x){ *p = f2bf(x); }

// online logsumexp accumulate: state (m, s) means LSE = m + log(s)
__device__ __forceinline__ void ons(float x, float& m, float& s){
  if (x <= m) { s += __expf(x - m); }
  else        { s = s * __expf(m - x) + 1.0f; m = x; }
}
__device__ __forceinline__ void comb(float& m, float& s, float m2, float s2){
  if (m2 <= m) { s += s2 * __expf(m2 - m); }
  else         { s = s * __expf(m - m2) + s2; m = m2; }
}

// ---------------- GEMM: S[b,i,j] = sum_c A[b,i,c]*B[b,j,c]; fp32 in, bf16 MFMA, ST out ------
template<typename ST>
__global__ void __launch_bounds__(256) gemm_k(
    const float* __restrict__ A, const float* __restrict__ Bm,
    ST* __restrict__ S, long srow, long sbatch)
{
  int wid  = (blockIdx.x * 256 + threadIdx.x) >> 6;  // 1 wave = one 64x64 tile
  int lane = threadIdx.x & 63;
  int b  = wid >> 10;          // 32*32 = 1024 tiles per batch
  int tt = wid & 1023;
  int i0 = (tt >> 5) << 6;
  int j0 = (tt & 31) << 6;
  int ln = lane & 15, qd = lane >> 4;
  const float* Ab = A  + (size_t)b * Mn * Cn;
  const float* Bb = Bm + (size_t)b * Nn * Cn;

  v4f acc[4][4];
  #pragma unroll
  for (int r = 0; r < 4; ++r)
    #pragma unroll
    for (int c = 0; c < 4; ++c)
      #pragma unroll
      for (int e = 0; e < 4; ++e) acc[r][c][e] = 0.0f;

  #pragma unroll
  for (int k0 = 0; k0 < Cn; k0 += 32){
    int kk = k0 + qd * 8;
    v8bf af[4], bfr[4];
    #pragma unroll
    for (int r = 0; r < 4; ++r){
      const float* p = Ab + (size_t)(i0 + r*16 + ln) * Cn + kk;
      v4f lo = *(const v4f*)p, hi = *(const v4f*)(p + 4);
      #pragma unroll
      for (int e = 0; e < 4; ++e){ af[r][e] = (__bf16)lo[e]; af[r][e+4] = (__bf16)hi[e]; }
    }
    #pragma unroll
    for (int c = 0; c < 4; ++c){
      const float* p = Bb + (size_t)(j0 + c*16 + ln) * Cn + kk;
      v4f lo = *(const v4f*)p, hi = *(const v4f*)(p + 4);
      #pragma unroll
      for (int e = 0; e < 4; ++e){ bfr[c][e] = (__bf16)lo[e]; bfr[c][e+4] = (__bf16)hi[e]; }
    }
    #pragma unroll
    for (int r = 0; r < 4; ++r)
      #pragma unroll
      for (int c = 0; c < 4; ++c)
        acc[r][c] = __builtin_amdgcn_mfma_f32_16x16x32_bf16(af[r], bfr[c], acc[r][c], 0, 0, 0);
  }

  ST* Sb = S + (size_t)b * sbatch;
  #pragma unroll
  for (int r = 0; r < 4; ++r){
    #pragma unroll
    for (int e = 0; e < 4; ++e){
      int row = i0 + r*16 + qd*4 + e;   // C/D: col=lane&15, row=quad*4+reg  [HW-verified by R3 probe]
      #pragma unroll
      for (int c = 0; c < 4; ++c)
        stS(Sb + (size_t)row * srow + (j0 + c*16 + ln), acc[r][c][e]);
    }
  }
}

// ---------------- row pass: u[b,i] = log_mu[i] - LSE_j(Z[b,i,j] + v[b,j]) -------------------
template<typename ST>
__global__ void __launch_bounds__(256) row_pass(
    const ST* __restrict__ S, long srow, long sbatch,
    const float* __restrict__ v, float* __restrict__ u,
    const float* __restrict__ binp)
{
  int i = blockIdx.x, b = blockIdx.y, t = threadIdx.x;
  const float* vb = v + (size_t)b * Np1;
  float m = -3.0e38f, s = 0.0f;
  if (i < Mn){
    const ST* Sr = S + (size_t)b * sbatch + (size_t)i * srow;
    #pragma unroll
    for (int jj = 0; jj < Nn / 256; ++jj){
      int j = jj * 256 + t;
      ons(ldS(Sr + j) + vb[j], m, s);
    }
  } else {
    // dustbin row: Z[M,j] = bin for all j -> bin + LSE(v)
    for (int j = t; j <= Nn; j += 256) ons(vb[j], m, s);
  }
  #pragma unroll
  for (int off = 32; off > 0; off >>= 1){
    float m2 = __shfl_down(m, off);
    float s2 = __shfl_down(s, off);
    comb(m, s, m2, s2);
  }
  __shared__ float sm[4], ss[4];
  int w = t >> 6;
  if ((t & 63) == 0){ sm[w] = m; ss[w] = s; }
  __syncthreads();
  if (t == 0){
    #pragma unroll
    for (int w2 = 1; w2 < 4; ++w2) comb(m, s, sm[w2], ss[w2]);
    float bin = binp[0];
    if (i < Mn){
      comb(m, s, bin + vb[Nn], 1.0f);               // dustbin column term
      u[(size_t)b * Mp1 + i] = NORM - (m + __logf(s));
    } else {
      u[(size_t)b * Mp1 + Mn] = LOGBIN - (bin + m + __logf(s));
    }
  }
}

// ---------------- col pass: v[b,j] = log_nu[j] - LSE_i(Z[b,i,j] + u[b,i]) -------------------
template<typename ST>
__global__ void __launch_bounds__(1024) col_pass(
    const ST* __restrict__ S, long srow, long sbatch,
    const float* __restrict__ u, float* __restrict__ v,
    const float* __restrict__ binp)
{
  int jt = blockIdx.x, b = blockIdx.y, t = threadIdx.x;
  const float* ub = u + (size_t)b * Mp1;
  __shared__ float sm[16][64];
  __shared__ float ss[16][64];
  if (jt < Nn / 64){
    int c = t & 63, rg = t >> 6;       // 64 cols x 16 row-groups
    int j = jt * 64 + c;
    const ST* Sc = S + (size_t)b * sbatch + j;
    float m = -3.0e38f, s = 0.0f;
    #pragma unroll 8
    for (int i = rg; i < Mn; i += 16)
      ons(ldS(Sc + (size_t)i * srow) + ub[i], m, s);
    sm[rg][c] = m; ss[rg][c] = s;
    __syncthreads();
    if (rg == 0){
      #pragma unroll
      for (int r = 1; r < 16; ++r) comb(m, s, sm[r][c], ss[r][c]);
      float bin = binp[0];
      comb(m, s, bin + ub[Mn], 1.0f);               // dustbin row term
      v[(size_t)b * Np1 + j] = NORM - (m + __logf(s));
    }
  } else {
    // dustbin column: Z[i,N] = bin for all i -> bin + LSE(u)
    float m = -3.0e38f, s = 0.0f;
    for (int i = t; i <= Mn; i += 1024) ons(ub[i], m, s);
    #pragma unroll
    for (int off = 32; off > 0; off >>= 1){
      float m2 = __shfl_down(m, off);
      float s2 = __shfl_down(s, off);
      comb(m, s, m2, s2);
    }
    int w = t >> 6;
    if ((t & 63) == 0){ sm[0][w] = m; ss[0][w] = s; }
    __syncthreads();
    if (t == 0){
      #pragma unroll
      for (int w2 = 1; w2 < 16; ++w2) comb(m, s, sm[0][w2], ss[0][w2]);
      float bin = binp[0];
      v[(size_t)b * Np1 + Nn] = LOGBIN - (bin + m + __logf(s));
    }
  }
}

// ---------------- final: out[b,i,j] = S + u[i] + v[j] - norm (fp32 out) ---------------------
// Works for both paths: ST=ushort (S in ws) and ST=float with S aliasing out (element-wise
// same-position read->write, no cross-thread hazard).
template<typename ST>
__global__ void __launch_bounds__(256) final_k(
    const ST* __restrict__ S, long srow, long sbatch,
    float* __restrict__ out, const float* __restrict__ u,
    const float* __restrict__ v, const float* __restrict__ binp)
{
  int i = blockIdx.x, b = blockIdx.y, t = threadIdx.x;
  float bin = binp[0];
  float ui = u[(size_t)b * Mp1 + i];
  const float* vb = v + (size_t)b * Np1;
  float* ob = out + ((size_t)b * Mp1 + i) * Np1;
  if (i < Mn){
    const ST* Sr = S + (size_t)b * sbatch + (size_t)i * srow;
    for (int j = t; j < Nn; j += 256)
      ob[j] = ldS(Sr + j) + ui + vb[j] - NORM;
    if (t == 0) ob[Nn] = bin + ui + vb[Nn] - NORM;
  } else {
    for (int j = t; j <= Nn; j += 256)
      ob[j] = bin + ui + vb[j] - NORM;
  }
}

__global__ void zero_uv(float* uv){
  int t = blockIdx.x * 256 + threadIdx.x;
  if (t < 2 * Bn * Mp1) uv[t] = 0.0f;
}

extern "C" void kernel_launch(void* const* d_in, const int* in_sizes, int n_in,
                              void* d_out, int out_size, void* d_ws, size_t ws_size,
                              hipStream_t stream)
{
  const float* A    = (const float*)d_in[0];
  const float* Bm   = (const float*)d_in[1];
  const float* binp = (const float*)d_in[2];
  float* out = (float*)d_out;

  const size_t S_bytes  = (size_t)Bn * Mn * Nn * 2;      // bf16 S in ws
  const size_t uv_bytes = (size_t)2 * Bn * Mp1 * 4;
  bool useW = ws_size >= S_bytes + uv_bytes;             // constant across calls

  float* u;
  unsigned short* Sw = nullptr;
  if (useW){
    Sw = (unsigned short*)d_ws;
    u  = (float*)((char*)d_ws + S_bytes);
  } else {
    u  = (float*)d_ws;
  }
  float* v = u + (size_t)Bn * Mp1;

  zero_uv<<<(2 * Bn * Mp1 + 255) / 256, 256, 0, stream>>>(u);

  if (useW){
    const long srow = Nn, sbatch = (long)Mn * Nn;
    gemm_k<unsigned short><<<(Bn * 32 * 32) / 4, 256, 0, stream>>>(A, Bm, Sw, srow, sbatch);
    for (int it = 0; it < SINK_ITERS; ++it){
      row_pass<unsigned short><<<dim3(Mp1, Bn), 256, 0, stream>>>(Sw, srow, sbatch, v, u, binp);
      col_pass<unsigned short><<<dim3(Nn / 64 + 1, Bn), 1024, 0, stream>>>(Sw, srow, sbatch, u, v, binp);
    }
    final_k<unsigned short><<<dim3(Mp1, Bn), 256, 0, stream>>>(Sw, srow, sbatch, out, u, v, binp);
  } else {
    // fallback: fp32 S stored in-place inside d_out at stride N+1
    const long srow = Np1, sbatch = (long)Mp1 * Np1;
    gemm_k<float><<<(Bn * 32 * 32) / 4, 256, 0, stream>>>(A, Bm, out, srow, sbatch);
    for (int it = 0; it < SINK_ITERS; ++it){
      row_pass<float><<<dim3(Mp1, Bn), 256, 0, stream>>>(out, srow, sbatch, v, u, binp);
      col_pass<float><<<dim3(Nn / 64 + 1, Bn), 1024, 0, stream>>>(out, srow, sbatch, u, v, binp);
    }
    final_k<float><<<dim3(Mp1, Bn), 256, 0, stream>>>(out, srow, sbatch, out, u, v, binp);
  }
}

// Round 5
// 1301.900 us; speedup vs baseline: 1.4918x; 1.4918x over previous
//
#include <hip/hip_runtime.h>

#define Bn 8
#define Mn 2048
#define Nn 2048
#define Cn 256
#define Np1 2049
#define Mp1 2049
#define UVS 2056                        /* padded u/v row stride (16B-aligned per batch) */
#define SINK_ITERS 20
#define NORM   (-8.3177661667193428f)   /* -log(4096) */
#define LOGBIN (-0.6931471805599453f)   /* log(2048) - log(4096) */

typedef __bf16 v8bf __attribute__((ext_vector_type(8)));
typedef float  v4f  __attribute__((ext_vector_type(4)));
typedef unsigned short v8u __attribute__((ext_vector_type(8)));

__device__ __forceinline__ float bf2f(unsigned short h){
  return __uint_as_float(((unsigned)h) << 16);
}
__device__ __forceinline__ unsigned short f2bf(float f){
  unsigned u = __float_as_uint(f);
  return (unsigned short)((u + 0x7FFFu + ((u >> 16) & 1u)) >> 16);
}
__device__ __forceinline__ float ldS(const float* p){ return *p; }
__device__ __forceinline__ float ldS(const unsigned short* p){ return bf2f(*p); }
__device__ __forceinline__ void  stS(float* p, float x){ *p = x; }
__device__ __forceinline__ void  stS(unsigned short* p, float x){ *p = f2bf(x); }

// online logsumexp accumulate (branchy; used only in small reductions / fallback)
__device__ __forceinline__ void ons(float x, float& m, float& s){
  if (x <= m) { s += __expf(x - m); }
  else        { s = s * __expf(m - x) + 1.0f; m = x; }
}
__device__ __forceinline__ void comb(float& m, float& s, float m2, float s2){
  if (m2 <= m) { s += s2 * __expf(m2 - m); }
  else         { s = s * __expf(m - m2) + s2; m = m2; }
}

// ---------------- GEMM: S[b,i,j] = sum_c A[b,i,c]*B[b,j,c]; fp32 in, bf16 MFMA, ST out ------
template<typename ST>
__global__ void __launch_bounds__(256) gemm_k(
    const float* __restrict__ A, const float* __restrict__ Bm,
    ST* __restrict__ S, long srow, long sbatch)
{
  int wid  = (blockIdx.x * 256 + threadIdx.x) >> 6;  // 1 wave = one 64x64 tile
  int lane = threadIdx.x & 63;
  int b  = wid >> 10;          // 32*32 = 1024 tiles per batch
  int tt = wid & 1023;
  int i0 = (tt >> 5) << 6;
  int j0 = (tt & 31) << 6;
  int ln = lane & 15, qd = lane >> 4;
  const float* Ab = A  + (size_t)b * Mn * Cn;
  const float* Bb = Bm + (size_t)b * Nn * Cn;

  v4f acc[4][4];
  #pragma unroll
  for (int r = 0; r < 4; ++r)
    #pragma unroll
    for (int c = 0; c < 4; ++c)
      #pragma unroll
      for (int e = 0; e < 4; ++e) acc[r][c][e] = 0.0f;

  #pragma unroll
  for (int k0 = 0; k0 < Cn; k0 += 32){
    int kk = k0 + qd * 8;
    v8bf af[4], bfr[4];
    #pragma unroll
    for (int r = 0; r < 4; ++r){
      const float* p = Ab + (size_t)(i0 + r*16 + ln) * Cn + kk;
      v4f lo = *(const v4f*)p, hi = *(const v4f*)(p + 4);
      #pragma unroll
      for (int e = 0; e < 4; ++e){ af[r][e] = (__bf16)lo[e]; af[r][e+4] = (__bf16)hi[e]; }
    }
    #pragma unroll
    for (int c = 0; c < 4; ++c){
      const float* p = Bb + (size_t)(j0 + c*16 + ln) * Cn + kk;
      v4f lo = *(const v4f*)p, hi = *(const v4f*)(p + 4);
      #pragma unroll
      for (int e = 0; e < 4; ++e){ bfr[c][e] = (__bf16)lo[e]; bfr[c][e+4] = (__bf16)hi[e]; }
    }
    #pragma unroll
    for (int r = 0; r < 4; ++r)
      #pragma unroll
      for (int c = 0; c < 4; ++c)
        acc[r][c] = __builtin_amdgcn_mfma_f32_16x16x32_bf16(af[r], bfr[c], acc[r][c], 0, 0, 0);
  }

  ST* Sb = S + (size_t)b * sbatch;
  #pragma unroll
  for (int r = 0; r < 4; ++r){
    #pragma unroll
    for (int e = 0; e < 4; ++e){
      int row = i0 + r*16 + qd*4 + e;   // C/D: col=lane&15, row=quad*4+reg  [HW-verified]
      #pragma unroll
      for (int c = 0; c < 4; ++c)
        stS(Sb + (size_t)row * srow + (j0 + c*16 + ln), acc[r][c][e]);
    }
  }
}

// ============== FAST PATH (bf16 S in workspace) =============================================

// row pass: u[b,i] = log_mu[i] - LSE_j(Z[b,i,j] + v[b,j]); 256 thr, ushort8 loads, 2-phase LSE
__global__ void __launch_bounds__(256) row_pass_v(
    const unsigned short* __restrict__ S, const float* __restrict__ v,
    float* __restrict__ u, const float* __restrict__ binp)
{
  int i = blockIdx.x, b = blockIdx.y, t = threadIdx.x;
  const float* vb = v + (size_t)b * UVS;
  float x[9];
  int K;
  if (i < Mn){
    const unsigned short* Sr = S + ((size_t)b * Mn + i) * Nn;
    int j0 = t * 8;
    v8u sv = *(const v8u*)(Sr + j0);
    v4f va = *(const v4f*)(vb + j0);
    v4f vc = *(const v4f*)(vb + j0 + 4);
    #pragma unroll
    for (int c = 0; c < 4; ++c){ x[c] = bf2f(sv[c]) + va[c]; x[c+4] = bf2f(sv[c+4]) + vc[c]; }
    K = 8;
  } else {
    // dustbin row: Z[M,j] = bin for all j -> bin + LSE(v[0..N])
    #pragma unroll
    for (int k = 0; k < 9; ++k){
      int j = t + k * 256;
      x[k] = (j <= Nn) ? vb[j] : -3.0e38f;
    }
    K = 9;
  }
  float m = x[0];
  #pragma unroll
  for (int k = 1; k < 9; ++k) if (k < K) m = fmaxf(m, x[k]);
  #pragma unroll
  for (int off = 32; off > 0; off >>= 1) m = fmaxf(m, __shfl_down(m, off));
  __shared__ float red[8];
  int w = t >> 6;
  if ((t & 63) == 0) red[w] = m;
  __syncthreads();
  float M = fmaxf(fmaxf(red[0], red[1]), fmaxf(red[2], red[3]));
  float s = 0.0f;
  #pragma unroll
  for (int k = 0; k < 9; ++k) if (k < K) s += __expf(x[k] - M);
  #pragma unroll
  for (int off = 32; off > 0; off >>= 1) s += __shfl_down(s, off);
  __syncthreads();
  if ((t & 63) == 0) red[w] = s;
  __syncthreads();
  if (t == 0){
    float Ss = red[0] + red[1] + red[2] + red[3];
    float bin = binp[0];
    if (i < Mn){
      comb(M, Ss, bin + vb[Nn], 1.0f);              // dustbin column term
      u[(size_t)b * UVS + i] = NORM - (M + __logf(Ss));
    } else {
      u[(size_t)b * UVS + Mn] = LOGBIN - (bin + M + __logf(Ss));
    }
  }
}

// col pass: v[b,j] = log_nu[j] - LSE_i(Z[b,i,j] + u[b,i]); 64 cols/block, ushort8 loads,
// branchless online per-column states, padded-LDS combine.
__global__ void __launch_bounds__(256) col_pass_v(
    const unsigned short* __restrict__ S, const float* __restrict__ u,
    float* __restrict__ v, const float* __restrict__ binp)
{
  int blk = blockIdx.x, b = blockIdx.y, t = threadIdx.x;
  const float* ub = u + (size_t)b * UVS;
  __shared__ float lm[32][65];
  __shared__ float ls[32][65];
  __shared__ float red[16];
  if (blk < Nn / 64){
    int tx = t & 7, ty = t >> 3;                 // 8 col-octets x 32 row-groups
    int j0 = blk * 64 + tx * 8;
    const unsigned short* Sb = S + (size_t)b * Mn * Nn;
    float m[8], s[8];
    #pragma unroll
    for (int c = 0; c < 8; ++c){ m[c] = -3.0e38f; s[c] = 0.0f; }
    for (int i = ty; i < Mn; i += 32){
      v8u sv = *(const v8u*)(Sb + (size_t)i * Nn + j0);
      float ui = ub[i];
      #pragma unroll
      for (int c = 0; c < 8; ++c){
        float x  = bf2f(sv[c]) + ui;
        float mn = fmaxf(m[c], x);
        s[c] = s[c] * __expf(m[c] - mn) + __expf(x - mn);
        m[c] = mn;
      }
    }
    #pragma unroll
    for (int c = 0; c < 8; ++c){ lm[ty][tx*8 + c] = m[c]; ls[ty][tx*8 + c] = s[c]; }
    __syncthreads();
    if (t < 64){
      float M = -3.0e38f, Ss = 0.0f;
      #pragma unroll 4
      for (int rg = 0; rg < 32; ++rg) comb(M, Ss, lm[rg][t], ls[rg][t]);
      float bin = binp[0];
      comb(M, Ss, bin + ub[Mn], 1.0f);              // dustbin row term
      v[(size_t)b * UVS + blk * 64 + t] = NORM - (M + __logf(Ss));
    }
  } else {
    // dustbin column: Z[i,N] = bin for all i -> bin + LSE(u[0..M])
    float x[9];
    #pragma unroll
    for (int k = 0; k < 9; ++k){
      int j = t + k * 256;
      x[k] = (j <= Mn) ? ub[j] : -3.0e38f;
    }
    float m = x[0];
    #pragma unroll
    for (int k = 1; k < 9; ++k) m = fmaxf(m, x[k]);
    #pragma unroll
    for (int off = 32; off > 0; off >>= 1) m = fmaxf(m, __shfl_down(m, off));
    int w = t >> 6;
    if ((t & 63) == 0) red[w] = m;
    __syncthreads();
    float M = fmaxf(fmaxf(red[0], red[1]), fmaxf(red[2], red[3]));
    float s = 0.0f;
    #pragma unroll
    for (int k = 0; k < 9; ++k) s += __expf(x[k] - M);
    #pragma unroll
    for (int off = 32; off > 0; off >>= 1) s += __shfl_down(s, off);
    __syncthreads();
    if ((t & 63) == 0) red[w] = s;
    __syncthreads();
    if (t == 0){
      float Ss = red[0] + red[1] + red[2] + red[3];
      float bin = binp[0];
      v[(size_t)b * UVS + Nn] = LOGBIN - (bin + M + __logf(Ss));
    }
  }
}

// final: out[b,i,j] = S + u[i] + v[j] - norm (fp32 out), vectorized S/v loads
__global__ void __launch_bounds__(256) final_v(
    const unsigned short* __restrict__ S, float* __restrict__ out,
    const float* __restrict__ u, const float* __restrict__ v,
    const float* __restrict__ binp)
{
  int i = blockIdx.x, b = blockIdx.y, t = threadIdx.x;
  float bin = binp[0];
  const float* vb = v + (size_t)b * UVS;
  float ui = u[(size_t)b * UVS + i];
  float* ob = out + ((size_t)b * Mp1 + i) * Np1;
  if (i < Mn){
    const unsigned short* Sr = S + ((size_t)b * Mn + i) * Nn;
    int j0 = t * 8;
    v8u sv = *(const v8u*)(Sr + j0);
    v4f va = *(const v4f*)(vb + j0);
    v4f vc = *(const v4f*)(vb + j0 + 4);
    #pragma unroll
    for (int c = 0; c < 4; ++c) ob[j0 + c]     = bf2f(sv[c])   + ui + va[c] - NORM;
    #pragma unroll
    for (int c = 0; c < 4; ++c) ob[j0 + 4 + c] = bf2f(sv[c+4]) + ui + vc[c] - NORM;
    if (t == 0) ob[Nn] = bin + ui + vb[Nn] - NORM;
  } else {
    for (int j = t; j <= Nn; j += 256) ob[j] = bin + ui + vb[j] - NORM;
  }
}

// ============== FALLBACK PATH (fp32 S in-place in d_out; scalar, correctness-first) =========

template<typename ST>
__global__ void __launch_bounds__(256) row_pass(
    const ST* __restrict__ S, long srow, long sbatch,
    const float* __restrict__ v, float* __restrict__ u,
    const float* __restrict__ binp)
{
  int i = blockIdx.x, b = blockIdx.y, t = threadIdx.x;
  const float* vb = v + (size_t)b * UVS;
  float m = -3.0e38f, s = 0.0f;
  if (i < Mn){
    const ST* Sr = S + (size_t)b * sbatch + (size_t)i * srow;
    #pragma unroll
    for (int jj = 0; jj < Nn / 256; ++jj){
      int j = jj * 256 + t;
      ons(ldS(Sr + j) + vb[j], m, s);
    }
  } else {
    for (int j = t; j <= Nn; j += 256) ons(vb[j], m, s);
  }
  #pragma unroll
  for (int off = 32; off > 0; off >>= 1){
    float m2 = __shfl_down(m, off);
    float s2 = __shfl_down(s, off);
    comb(m, s, m2, s2);
  }
  __shared__ float sm[4], ss[4];
  int w = t >> 6;
  if ((t & 63) == 0){ sm[w] = m; ss[w] = s; }
  __syncthreads();
  if (t == 0){
    #pragma unroll
    for (int w2 = 1; w2 < 4; ++w2) comb(m, s, sm[w2], ss[w2]);
    float bin = binp[0];
    if (i < Mn){
      comb(m, s, bin + vb[Nn], 1.0f);
      u[(size_t)b * UVS + i] = NORM - (m + __logf(s));
    } else {
      u[(size_t)b * UVS + Mn] = LOGBIN - (bin + m + __logf(s));
    }
  }
}

template<typename ST>
__global__ void __launch_bounds__(1024) col_pass(
    const ST* __restrict__ S, long srow, long sbatch,
    const float* __restrict__ u, float* __restrict__ v,
    const float* __restrict__ binp)
{
  int jt = blockIdx.x, b = blockIdx.y, t = threadIdx.x;
  const float* ub = u + (size_t)b * UVS;
  __shared__ float sm[16][64];
  __shared__ float ss[16][64];
  if (jt < Nn / 64){
    int c = t & 63, rg = t >> 6;
    int j = jt * 64 + c;
    const ST* Sc = S + (size_t)b * sbatch + j;
    float m = -3.0e38f, s = 0.0f;
    #pragma unroll 8
    for (int i = rg; i < Mn; i += 16)
      ons(ldS(Sc + (size_t)i * srow) + ub[i], m, s);
    sm[rg][c] = m; ss[rg][c] = s;
    __syncthreads();
    if (rg == 0){
      #pragma unroll
      for (int r = 1; r < 16; ++r) comb(m, s, sm[r][c], ss[r][c]);
      float bin = binp[0];
      comb(m, s, bin + ub[Mn], 1.0f);
      v[(size_t)b * UVS + j] = NORM - (m + __logf(s));
    }
  } else {
    float m = -3.0e38f, s = 0.0f;
    for (int i = t; i <= Mn; i += 1024) ons(ub[i], m, s);
    #pragma unroll
    for (int off = 32; off > 0; off >>= 1){
      float m2 = __shfl_down(m, off);
      float s2 = __shfl_down(s, off);
      comb(m, s, m2, s2);
    }
    int w = t >> 6;
    if ((t & 63) == 0){ sm[0][w] = m; ss[0][w] = s; }
    __syncthreads();
    if (t == 0){
      #pragma unroll
      for (int w2 = 1; w2 < 16; ++w2) comb(m, s, sm[0][w2], ss[0][w2]);
      float bin = binp[0];
      v[(size_t)b * UVS + Nn] = LOGBIN - (bin + m + __logf(s));
    }
  }
}

template<typename ST>
__global__ void __launch_bounds__(256) final_k(
    const ST* __restrict__ S, long srow, long sbatch,
    float* __restrict__ out, const float* __restrict__ u,
    const float* __restrict__ v, const float* __restrict__ binp)
{
  int i = blockIdx.x, b = blockIdx.y, t = threadIdx.x;
  float bin = binp[0];
  float ui = u[(size_t)b * UVS + i];
  const float* vb = v + (size_t)b * UVS;
  float* ob = out + ((size_t)b * Mp1 + i) * Np1;
  if (i < Mn){
    const ST* Sr = S + (size_t)b * sbatch + (size_t)i * srow;
    for (int j = t; j < Nn; j += 256)
      ob[j] = ldS(Sr + j) + ui + vb[j] - NORM;
    if (t == 0) ob[Nn] = bin + ui + vb[Nn] - NORM;
  } else {
    for (int j = t; j <= Nn; j += 256)
      ob[j] = bin + ui + vb[j] - NORM;
  }
}

__global__ void zero_uv(float* uv){
  int t = blockIdx.x * 256 + threadIdx.x;
  if (t < 2 * Bn * UVS) uv[t] = 0.0f;
}

extern "C" void kernel_launch(void* const* d_in, const int* in_sizes, int n_in,
                              void* d_out, int out_size, void* d_ws, size_t ws_size,
                              hipStream_t stream)
{
  const float* A    = (const float*)d_in[0];
  const float* Bm   = (const float*)d_in[1];
  const float* binp = (const float*)d_in[2];
  float* out = (float*)d_out;

  const size_t S_bytes  = (size_t)Bn * Mn * Nn * 2;      // bf16 S in ws (64 MiB)
  const size_t uv_bytes = (size_t)2 * Bn * UVS * 4;
  bool useW = ws_size >= S_bytes + uv_bytes;             // constant across calls

  float* u;
  unsigned short* Sw = nullptr;
  if (useW){
    Sw = (unsigned short*)d_ws;
    u  = (float*)((char*)d_ws + S_bytes);
  } else {
    u  = (float*)d_ws;
  }
  float* v = u + (size_t)Bn * UVS;

  zero_uv<<<(2 * Bn * UVS + 255) / 256, 256, 0, stream>>>(u);

  if (useW){
    gemm_k<unsigned short><<<(Bn * 32 * 32) / 4, 256, 0, stream>>>(A, Bm, Sw, Nn, (long)Mn * Nn);
    for (int it = 0; it < SINK_ITERS; ++it){
      row_pass_v<<<dim3(Mp1, Bn), 256, 0, stream>>>(Sw, v, u, binp);
      col_pass_v<<<dim3(Nn / 64 + 1, Bn), 256, 0, stream>>>(Sw, u, v, binp);
    }
    final_v<<<dim3(Mp1, Bn), 256, 0, stream>>>(Sw, out, u, v, binp);
  } else {
    // fallback: fp32 S stored in-place inside d_out at stride N+1
    const long srow = Np1, sbatch = (long)Mp1 * Np1;
    gemm_k<float><<<(Bn * 32 * 32) / 4, 256, 0, stream>>>(A, Bm, out, srow, sbatch);
    for (int it = 0; it < SINK_ITERS; ++it){
      row_pass<float><<<dim3(Mp1, Bn), 256, 0, stream>>>(out, srow, sbatch, v, u, binp);
      col_pass<float><<<dim3(Nn / 64 + 1, Bn), 1024, 0, stream>>>(out, srow, sbatch, u, v, binp);
    }
    final_k<float><<<dim3(Mp1, Bn), 256, 0, stream>>>(out, srow, sbatch, out, u, v, binp);
  }
}